// Round 10
// baseline (762.502 us; speedup 1.0000x reference)
//
#include <hip/hip_runtime.h>

typedef _Float16 f16;
typedef _Float16 f16x8 __attribute__((ext_vector_type(8)));
typedef _Float16 f16x4 __attribute__((ext_vector_type(4)));
typedef float f32x4 __attribute__((ext_vector_type(4)));

#define NH 4
#define HD 256
#define BB 4
#define SS 2048
#define HID 1152
#define QKV_N 1536
#define ODIM (NH * HD)

#define QKV16_OFF 0L
#define HID16_OFF 25165824L
#define OBUF_OFF 0L
#define OPART_OFF 16777216L
#define ML_OFF 44040192L
#define QB_OFF 50331648L
#define KB_OFF 67108864L
#define VT_OFF 71303168L
#define WQKVT_OFF 75497472L
#define WOT_OFF 79036416L

// async global->LDS, 16B per lane; LDS dest = wave-uniform base + lane*16
#define GLL16(gp, lp)                                                      \
  __builtin_amdgcn_global_load_lds(                                       \
      (const __attribute__((address_space(1))) char*)(gp),                \
      (__attribute__((address_space(3))) char*)(lp), 16, 0, 0)

// ---------------------------------------------------------------------------
// fp32 -> fp16 bulk convert (vectorized, grid-stride)
// ---------------------------------------------------------------------------
__global__ __launch_bounds__(256) void cvt_f32_to_f16(
    const float* __restrict__ s, f16* __restrict__ d, long n) {
  long i = ((long)blockIdx.x * 256 + threadIdx.x) * 8;
  long stride = (long)gridDim.x * 256 * 8;
  for (; i < n; i += stride) {
    float4 a = *(const float4*)(s + i);
    float4 b = *(const float4*)(s + i + 4);
    f16x8 h = {(f16)a.x, (f16)a.y, (f16)a.z, (f16)a.w,
               (f16)b.x, (f16)b.y, (f16)b.z, (f16)b.w};
    *(f16x8*)(d + i) = h;
  }
}

// ---------------------------------------------------------------------------
// Transpose + convert to fp16:  dst[c][r] = (f16) src[r][c]
// ---------------------------------------------------------------------------
template <typename ST>
__global__ __launch_bounds__(256) void transpose_cvt(
    const ST* __restrict__ src, long src_ld, long src_bs,
    f16* __restrict__ dst, long dst_ld, long dst_bs) {
  __shared__ float tile[32][33];
  src += (long)blockIdx.z * src_bs;
  dst += (long)blockIdx.z * dst_bs;
  int r0 = blockIdx.y * 32, c0 = blockIdx.x * 32;
  int tc = threadIdx.x & 31, tr = threadIdx.x >> 5;
#pragma unroll
  for (int i = 0; i < 4; ++i)
    tile[tr + i * 8][tc] = (float)src[(long)(r0 + tr + i * 8) * src_ld + c0 + tc];
  __syncthreads();
#pragma unroll
  for (int i = 0; i < 4; ++i)
    dst[(long)(c0 + tr + i * 8) * dst_ld + r0 + tc] = (f16)tile[tc][tr + i * 8];
}

// ---------------------------------------------------------------------------
// GEMM: C[M][N] = A[M][K] fp16 x Bt[N][K] fp16, C fp16 or fp32.
// m97 structure: 128x128 tile, BK=64, linear LDS, global_load_lds 16B.
// ---------------------------------------------------------------------------
template <typename CT>
__global__ __launch_bounds__(256, 3) void gemm_f16(
    const f16* __restrict__ A, const f16* __restrict__ Bt,
    CT* __restrict__ C, int K, int N) {
  __shared__ f16 As[128][64];
  __shared__ f16 Bs[128][64];
  int tid = threadIdx.x, wave = tid >> 6, lane = tid & 63;
  int l16 = lane & 15, lhi = lane >> 4;
  int wm = (wave >> 1) * 64, wn = (wave & 1) * 64;
  long bm = (long)blockIdx.x * 128, bn = (long)blockIdx.y * 128;
  f32x4 acc[4][4] = {};

  int srow = wave * 32 + (lane >> 3);
  int scol = (lane & 7) * 8;
  const f16* Ag = A + (bm + srow) * (long)K + scol;
  const f16* Bg = Bt + (bn + srow) * (long)K + scol;

  for (int k0 = 0; k0 < K; k0 += 64) {
#pragma unroll
    for (int i = 0; i < 4; ++i)
      GLL16(Ag + k0 + (long)i * 8 * K, &As[wave * 32 + i * 8][0]);
#pragma unroll
    for (int i = 0; i < 4; ++i)
      GLL16(Bg + k0 + (long)i * 8 * K, &Bs[wave * 32 + i * 8][0]);
    __syncthreads();
#pragma unroll
    for (int kb = 0; kb < 2; ++kb) {
      f16x8 af[4], bf[4];
#pragma unroll
      for (int i = 0; i < 4; ++i)
        af[i] = *(const f16x8*)&As[wm + i * 16 + l16][kb * 32 + lhi * 8];
#pragma unroll
      for (int j = 0; j < 4; ++j)
        bf[j] = *(const f16x8*)&Bs[wn + j * 16 + l16][kb * 32 + lhi * 8];
#pragma unroll
      for (int i = 0; i < 4; ++i)
#pragma unroll
        for (int j = 0; j < 4; ++j)
          acc[i][j] =
              __builtin_amdgcn_mfma_f32_16x16x32_f16(bf[j], af[i], acc[i][j], 0, 0, 0);
    }
    __syncthreads();
  }

#pragma unroll
  for (int i = 0; i < 4; ++i) {
    long m = bm + wm + i * 16 + l16;
#pragma unroll
    for (int j = 0; j < 4; ++j) {
      long n = bn + wn + j * 16 + lhi * 4;
      if constexpr (sizeof(CT) == 2) {
        f16x4 h = {(f16)acc[i][j][0], (f16)acc[i][j][1], (f16)acc[i][j][2],
                   (f16)acc[i][j][3]};
        *(f16x4*)&C[m * N + n] = h;
      } else {
        *(f32x4*)&C[m * N + n] = acc[i][j];
      }
    }
  }
}

// ---------------------------------------------------------------------------
// RMSNorm + RoPE + scale, qkv fp16 -> Q/K fp16
// ---------------------------------------------------------------------------
__device__ __forceinline__ void norm_rope_store(
    const f16* __restrict__ x, const float* __restrict__ w,
    const float* __restrict__ fc, const float* __restrict__ fs,
    f16* __restrict__ dst, float scale, int lane) {
  float x0 = (float)x[lane], x1 = (float)x[lane + 64];
  float x2 = (float)x[lane + 128], x3 = (float)x[lane + 192];
  float ss = x0 * x0 + x1 * x1 + x2 * x2 + x3 * x3;
#pragma unroll
  for (int m = 1; m < 64; m <<= 1) ss += __shfl_xor(ss, m, 64);
  float inv = rsqrtf(ss * (1.0f / 256.0f) + 1e-6f);
  x0 *= inv * (1.0f + w[lane]);
  x1 *= inv * (1.0f + w[lane + 64]);
  x2 *= inv * (1.0f + w[lane + 128]);
  x3 *= inv * (1.0f + w[lane + 192]);
  float c0 = fc[lane], s0 = fs[lane], c1 = fc[lane + 64], s1 = fs[lane + 64];
  dst[lane]       = (f16)((x0 * c0 - x2 * s0) * scale);
  dst[lane + 64]  = (f16)((x1 * c1 - x3 * s1) * scale);
  dst[lane + 128] = (f16)((x0 * s0 + x2 * c0) * scale);
  dst[lane + 192] = (f16)((x1 * s1 + x3 * c1) * scale);
}

__global__ __launch_bounds__(256) void qkv_post(
    const f16* __restrict__ qkv, const float* __restrict__ qnw,
    const float* __restrict__ knw, const float* __restrict__ fcos,
    const float* __restrict__ fsin, f16* __restrict__ Q, f16* __restrict__ Kb) {
  long row = blockIdx.x;
  int b = (int)(row >> 11), s = (int)(row & 2047);
  int wave = threadIdx.x >> 6, lane = threadIdx.x & 63;
  const f16* base = qkv + row * QKV_N;
  const float* fc = fcos + (long)s * 128;
  const float* fs = fsin + (long)s * 128;
  norm_rope_store(base + wave * HD, qnw, fc, fs,
                  Q + ((long)(b * NH + wave) * SS + s) * HD, 0.0625f, lane);
  if (wave == 0)
    norm_rope_store(base + NH * HD, knw, fc, fs, Kb + row * HD, 1.0f, lane);
}

// ---------------------------------------------------------------------------
// Flash attention, causal, GQA. R9 scheme (XCD-pinned grid, 63-item uniform
// kv-split, swizzled K LDS, swapped QK, in-reg softmax) with V fragments
// loaded DIRECTLY from global into registers (two batches of 8, issued early
// so QK/softmax/PV-half hide L2 latency) -> V LDS staging+reads eliminated.
// + T13 defer-max: skip O-rescale when max growth <= 8.
// ---------------------------------------------------------------------------
__global__ __launch_bounds__(256, 4) void attn_fwd(
    const f16* __restrict__ Q, const f16* __restrict__ Kb,
    const f16* __restrict__ Vt, f16* __restrict__ O,
    f16* __restrict__ Opart, float2* __restrict__ ml) {
  __shared__ f16 Klds[32 * 256];
  __shared__ f16 Plds[4][16][40];
  // --- XCD-pinned decode ---
  int bid = blockIdx.x;
  int xcd = bid & 7, slotid = bid >> 3;
  int b = xcd >> 1, par = xcd & 1;
  int h = slotid >> 5, ithalf = slotid & 31;
  int it = ithalf * 2 + par;
  if (it >= 63) return;

  int qb, t0, t1, slot = 0;
  bool split;
  if (it < 11) {
    qb = it; t0 = 0; t1 = 2 * qb + 2; split = false;
  } else {
    int j = it - 11, c, nch, lbase;
    if (j < 22) {
      qb = 11 + (j >> 1); c = j & 1; nch = 2; lbase = (qb - 11) * 2;
    } else {
      int jj = j - 22, q3 = jj / 3;
      qb = 22 + q3; c = jj - q3 * 3; nch = 3; lbase = 22 + q3 * 3;
    }
    int tiles = 2 * qb + 2;
    t0 = tiles * c / nch;
    t1 = tiles * (c + 1) / nch;
    split = true;
    slot = (b * NH + h) * 52 + lbase + c;
  }
  int tid = threadIdx.x, wave = tid >> 6, lane = tid & 63;
  int l16 = lane & 15, lhi = lane >> 4;
  int q0 = qb * 64 + wave * 16;

  const f16* Kg = Kb + (long)b * SS * HD;
  const f16* Vg = Vt + (long)b * HD * SS;

  // Q fragments (B-operand: q on lane&15, d-slice on lhi)
  f16x8 qf[8];
  const f16* Qbase = Q + ((long)(b * NH + h) * SS + q0 + l16) * HD + lhi * 8;
#pragma unroll
  for (int kb = 0; kb < 8; ++kb) qf[kb] = *(const f16x8*)(Qbase + kb * 32);

  f32x4 o[16] = {};
  float m_i = -1e30f, l_i = 0.f;

  // K staging (global reads linear/coalesced; LDS writes swizzled)
  int kr = tid >> 5, kc16 = (tid & 31) * 16;  // K rows kr+8i, col byte kc16
  char* kls = (char*)Klds;
  int kwsw = kc16 ^ (kr << 4);
  const char* krd = kls + l16 * 512;
  int kswz = (l16 & 7) << 4;
  // V frag base: row = nf*16 + l16, col elems kv0 + lhi*8
  const f16* vfb = Vg + (long)l16 * SS + lhi * 8;

  for (int t = t0; t < t1; ++t) {
    long kv0 = (long)t * 32;
    __syncthreads();  // prior tile's LDS reads complete
#pragma unroll
    for (int i = 0; i < 4; ++i) {
      uint4 kval = *(const uint4*)((const char*)(Kg + (kv0 + kr + 8 * i) * HD) + kc16);
      *(uint4*)(kls + (kr + 8 * i) * 512 + kwsw) = kval;
    }
    __syncthreads();  // staged tile visible

    // issue V batch 0 early: latency hidden under QK + softmax
    uint4 vr0[8], vr1[8];
#pragma unroll
    for (int nf = 0; nf < 8; ++nf)
      vr0[nf] = *(const uint4*)(vfb + (long)nf * 16 * SS + kv0);

    // QK^T swapped: mfma(K, Q) -> D[kv_local][q=l16]
    f32x4 sc[2] = {};
    __builtin_amdgcn_s_setprio(1);
#pragma unroll
    for (int kb = 0; kb < 8; ++kb) {
#pragma unroll
      for (int cf = 0; cf < 2; ++cf) {
        f16x8 kf = *(const f16x8*)(krd + cf * 8192 + ((kb * 64 + lhi * 16) ^ kswz));
        sc[cf] = __builtin_amdgcn_mfma_f32_16x16x32_f16(kf, qf[kb], sc[cf], 0, 0, 0);
      }
    }
    __builtin_amdgcn_s_setprio(0);

    // online softmax: lane owns q-row q0+l16, 8 scores in-register
    float p[8];
    float mx = -1e30f;
    int qrow = q0 + l16;
    if (t >= 2 * qb) {  // diagonal tiles need the causal mask
#pragma unroll
      for (int cf = 0; cf < 2; ++cf)
#pragma unroll
        for (int r = 0; r < 4; ++r) {
          int kv = (int)kv0 + cf * 16 + lhi * 4 + r;
          float s = (kv <= qrow) ? sc[cf][r] : -1e30f;
          p[cf * 4 + r] = s;
          mx = fmaxf(mx, s);
        }
    } else {
#pragma unroll
      for (int i = 0; i < 8; ++i) {
        float s = sc[i >> 2][i & 3];
        p[i] = s;
        mx = fmaxf(mx, s);
      }
    }
    mx = fmaxf(mx, __shfl_xor(mx, 16));
    mx = fmaxf(mx, __shfl_xor(mx, 32));

    if (__all(mx <= m_i + 8.f)) {  // T13 defer-max: no rescale needed
      float rs = 0.f;
#pragma unroll
      for (int i = 0; i < 8; ++i) {
        p[i] = __expf(p[i] - m_i);
        rs += p[i];
      }
      rs += __shfl_xor(rs, 16);
      rs += __shfl_xor(rs, 32);
      l_i += rs;
    } else {
      float mn = fmaxf(m_i, mx);
      float scl = __expf(m_i - mn);
      float rs = 0.f;
#pragma unroll
      for (int i = 0; i < 8; ++i) {
        p[i] = __expf(p[i] - mn);
        rs += p[i];
      }
      rs += __shfl_xor(rs, 16);
      rs += __shfl_xor(rs, 32);
      l_i = l_i * scl + rs;
      m_i = mn;
      float s0 = __shfl(scl, lhi * 4 + 0);
      float s1 = __shfl(scl, lhi * 4 + 1);
      float s2 = __shfl(scl, lhi * 4 + 2);
      float s3 = __shfl(scl, lhi * 4 + 3);
#pragma unroll
      for (int nf = 0; nf < 16; ++nf) {
        o[nf][0] *= s0;
        o[nf][1] *= s1;
        o[nf][2] *= s2;
        o[nf][3] *= s3;
      }
    }

    // P -> f16 into per-wave LDS [q][kv]
#pragma unroll
    for (int cf = 0; cf < 2; ++cf) {
      f16x4 hp = {(f16)p[cf * 4], (f16)p[cf * 4 + 1], (f16)p[cf * 4 + 2],
                  (f16)p[cf * 4 + 3]};
      *(f16x4*)&Plds[wave][l16][cf * 16 + lhi * 4] = hp;
    }

    // issue V batch 1; covered by PV half 0
#pragma unroll
    for (int nf = 0; nf < 8; ++nf)
      vr1[nf] = *(const uint4*)(vfb + (long)(nf + 8) * 16 * SS + kv0);

    // PV: o[q=lhi*4+r][d=nf*16+l16] += P x V
    f16x8 pa = *(const f16x8*)&Plds[wave][l16][lhi * 8];
    __builtin_amdgcn_s_setprio(1);
#pragma unroll
    for (int nf = 0; nf < 8; ++nf) {
      f16x8 vf = *(const f16x8*)&vr0[nf];
      o[nf] = __builtin_amdgcn_mfma_f32_16x16x32_f16(pa, vf, o[nf], 0, 0, 0);
    }
#pragma unroll
    for (int nf = 0; nf < 8; ++nf) {
      f16x8 vf = *(const f16x8*)&vr1[nf];
      o[nf + 8] = __builtin_amdgcn_mfma_f32_16x16x32_f16(pa, vf, o[nf + 8], 0, 0, 0);
    }
    __builtin_amdgcn_s_setprio(0);
  }

  // epilogue
  float inv = 1.0f / l_i;
  float i0 = __shfl(inv, lhi * 4 + 0);
  float i1 = __shfl(inv, lhi * 4 + 1);
  float i2 = __shfl(inv, lhi * 4 + 2);
  float i3 = __shfl(inv, lhi * 4 + 3);
  float ir[4] = {i0, i1, i2, i3};
  if (!split) {
#pragma unroll
    for (int r = 0; r < 4; ++r) {
      long srow = q0 + lhi * 4 + r;
      f16* Orow = O + ((long)b * SS + srow) * ODIM + h * HD + l16;
#pragma unroll
      for (int nf = 0; nf < 16; ++nf) Orow[nf * 16] = (f16)(o[nf][r] * ir[r]);
    }
  } else {
#pragma unroll
    for (int r = 0; r < 4; ++r) {
      int rloc = wave * 16 + lhi * 4 + r;
      f16* Prow = Opart + ((long)slot * 64 + rloc) * HD + l16;
#pragma unroll
      for (int nf = 0; nf < 16; ++nf) Prow[nf * 16] = (f16)(o[nf][r] * ir[r]);
    }
    if (lane < 16) {
      float2 v; v.x = m_i; v.y = l_i;
      ml[(long)slot * 64 + wave * 16 + lane] = v;
    }
  }
}

// ---------------------------------------------------------------------------
// Combine 2- or 3-way kv-split partials for qb in [11, 31].
// ---------------------------------------------------------------------------
__global__ __launch_bounds__(256) void attn_combine(
    const f16* __restrict__ Opart, const float2* __restrict__ ml,
    f16* __restrict__ O) {
  int x = blockIdx.x, h = blockIdx.y, b = blockIdx.z;
  int qb = 11 + x;
  int nch = (qb < 22) ? 2 : 3;
  int lbase = (qb < 22) ? (qb - 11) * 2 : 22 + (qb - 22) * 3;
  long slot0 = (long)(b * NH + h) * 52 + lbase;
  int tid = threadIdx.x;
  int r = tid >> 2, d0 = (tid & 3) * 64;
  float m[3], l[3], w[3];
  float M = -1e30f;
#pragma unroll
  for (int c = 0; c < 3; ++c)
    if (c < nch) {
      float2 v = ml[(slot0 + c) * 64 + r];
      m[c] = v.x; l[c] = v.y;
      M = fmaxf(M, v.x);
    }
  float sum = 0.f;
#pragma unroll
  for (int c = 0; c < 3; ++c)
    if (c < nch) { w[c] = l[c] * __expf(m[c] - M); sum += w[c]; }
  float inv = 1.0f / sum;
#pragma unroll
  for (int c = 0; c < 3; ++c)
    if (c < nch) w[c] *= inv;
  f16* Orow = O + ((long)b * SS + qb * 64 + r) * ODIM + h * HD + d0;
#pragma unroll
  for (int i = 0; i < 8; ++i) {
    float acc[8] = {};
#pragma unroll
    for (int c = 0; c < 3; ++c)
      if (c < nch) {
        f16x8 xv = *(const f16x8*)(Opart + ((slot0 + c) * 64 + r) * HD + d0 + i * 8);
#pragma unroll
        for (int j = 0; j < 8; ++j) acc[j] += w[c] * (float)xv[j];
      }
    f16x8 z;
#pragma unroll
    for (int j = 0; j < 8; ++j) z[j] = (f16)acc[j];
    *(f16x8*)(Orow + i * 8) = z;
  }
}

// ---------------------------------------------------------------------------
extern "C" void kernel_launch(void* const* d_in, const int* in_sizes, int n_in,
                              void* d_out, int out_size, void* d_ws, size_t ws_size,
                              hipStream_t stream) {
  const float* hidden = (const float*)d_in[0];
  const float* fcos = (const float*)d_in[2];
  const float* fsin = (const float*)d_in[3];
  const float* wqkv = (const float*)d_in[4];
  const float* qnw = (const float*)d_in[5];
  const float* knw = (const float*)d_in[6];
  const float* wo = (const float*)d_in[7];
  float* out = (float*)d_out;

  char* ws = (char*)d_ws;
  f16* qkv16 = (f16*)(ws + QKV16_OFF);
  f16* hid16 = (f16*)(ws + HID16_OFF);
  f16* Obuf = (f16*)(ws + OBUF_OFF);
  f16* Opart = (f16*)(ws + OPART_OFF);
  float2* ml = (float2*)(ws + ML_OFF);
  f16* Qb = (f16*)(ws + QB_OFF);
  f16* Kb = (f16*)(ws + KB_OFF);
  f16* Vt = (f16*)(ws + VT_OFF);
  f16* wqkvt = (f16*)(ws + WQKVT_OFF);
  f16* wot = (f16*)(ws + WOT_OFF);

  cvt_f32_to_f16<<<2048, 256, 0, stream>>>(hidden, hid16, (long)BB * SS * HID);

  transpose_cvt<float><<<dim3(QKV_N / 32, HID / 32, 1), 256, 0, stream>>>(
      wqkv, QKV_N, 0, wqkvt, HID, 0);
  transpose_cvt<float><<<dim3(HID / 32, ODIM / 32, 1), 256, 0, stream>>>(
      wo, HID, 0, wot, ODIM, 0);

  gemm_f16<f16><<<dim3(BB * SS / 128, QKV_N / 128), 256, 0, stream>>>(
      hid16, wqkvt, qkv16, HID, QKV_N);

  qkv_post<<<dim3(BB * SS), 256, 0, stream>>>(qkv16, qnw, knw, fcos, fsin, Qb, Kb);

  transpose_cvt<f16><<<dim3(HD / 32, SS / 32, BB), 256, 0, stream>>>(
      qkv16 + 1280, QKV_N, (long)SS * QKV_N, Vt, SS, (long)HD * SS);

  attn_fwd<<<dim3(1024), 256, 0, stream>>>(Qb, Kb, Vt, Obuf, Opart, ml);
  attn_combine<<<dim3(21, NH, BB), 256, 0, stream>>>(Opart, ml, Obuf);

  gemm_f16<float><<<dim3(BB * SS / 128, HID / 128), 256, 0, stream>>>(
      Obuf, wot, out, ODIM, HID);
}

// Round 11
// 528.476 us; speedup vs baseline: 1.4428x; 1.4428x over previous
//
#include <hip/hip_runtime.h>

typedef _Float16 f16;
typedef _Float16 f16x8 __attribute__((ext_vector_type(8)));
typedef _Float16 f16x4 __attribute__((ext_vector_type(4)));
typedef float f32x4 __attribute__((ext_vector_type(4)));

#define NH 4
#define HD 256
#define BB 4
#define SS 2048
#define HID 1152
#define QKV_N 1536
#define ODIM (NH * HD)

#define QKV16_OFF 0L
#define HID16_OFF 25165824L
#define OBUF_OFF 0L
#define OPART_OFF 16777216L
#define ML_OFF 44040192L
#define QB_OFF 50331648L
#define KB_OFF 67108864L
#define VT_OFF 71303168L
#define WQKVT_OFF 75497472L
#define WOT_OFF 79036416L

// async global->LDS, 16B per lane; LDS dest = wave-uniform base + lane*16
#define GLL16(gp, lp)                                                      \
  __builtin_amdgcn_global_load_lds(                                       \
      (const __attribute__((address_space(1))) char*)(gp),                \
      (__attribute__((address_space(3))) char*)(lp), 16, 0, 0)

// ---------------------------------------------------------------------------
// fp32 -> fp16 bulk convert (vectorized, grid-stride)
// ---------------------------------------------------------------------------
__global__ __launch_bounds__(256) void cvt_f32_to_f16(
    const float* __restrict__ s, f16* __restrict__ d, long n) {
  long i = ((long)blockIdx.x * 256 + threadIdx.x) * 8;
  long stride = (long)gridDim.x * 256 * 8;
  for (; i < n; i += stride) {
    float4 a = *(const float4*)(s + i);
    float4 b = *(const float4*)(s + i + 4);
    f16x8 h = {(f16)a.x, (f16)a.y, (f16)a.z, (f16)a.w,
               (f16)b.x, (f16)b.y, (f16)b.z, (f16)b.w};
    *(f16x8*)(d + i) = h;
  }
}

// ---------------------------------------------------------------------------
// Both weight transposes in one dispatch (z selects which).
// z=0: wqkv [1152][1536] -> wqkvt [1536][1152]
// z=1: wo   [1024][1152] -> wot   [1152][1024]
// ---------------------------------------------------------------------------
__global__ __launch_bounds__(256) void transpose_weights(
    const float* __restrict__ w1, f16* __restrict__ d1,
    const float* __restrict__ w2, f16* __restrict__ d2) {
  __shared__ float tile[32][33];
  const float* src;
  f16* dst;
  long sld, dld;
  if (blockIdx.z == 0) {
    src = w1; dst = d1; sld = QKV_N; dld = HID;
  } else {
    if (blockIdx.x >= HID / 32 || blockIdx.y >= ODIM / 32) return;
    src = w2; dst = d2; sld = HID; dld = ODIM;
  }
  int r0 = blockIdx.y * 32, c0 = blockIdx.x * 32;
  int tc = threadIdx.x & 31, tr = threadIdx.x >> 5;
#pragma unroll
  for (int i = 0; i < 4; ++i)
    tile[tr + i * 8][tc] = src[(long)(r0 + tr + i * 8) * sld + c0 + tc];
  __syncthreads();
#pragma unroll
  for (int i = 0; i < 4; ++i)
    dst[(long)(c0 + tr + i * 8) * dld + r0 + tc] = (f16)tile[tc][tr + i * 8];
}

// ---------------------------------------------------------------------------
// Transpose + convert to fp16:  dst[c][r] = (f16) src[r][c]   (V slice)
// ---------------------------------------------------------------------------
template <typename ST>
__global__ __launch_bounds__(256) void transpose_cvt(
    const ST* __restrict__ src, long src_ld, long src_bs,
    f16* __restrict__ dst, long dst_ld, long dst_bs) {
  __shared__ float tile[32][33];
  src += (long)blockIdx.z * src_bs;
  dst += (long)blockIdx.z * dst_bs;
  int r0 = blockIdx.y * 32, c0 = blockIdx.x * 32;
  int tc = threadIdx.x & 31, tr = threadIdx.x >> 5;
#pragma unroll
  for (int i = 0; i < 4; ++i)
    tile[tr + i * 8][tc] = (float)src[(long)(r0 + tr + i * 8) * src_ld + c0 + tc];
  __syncthreads();
#pragma unroll
  for (int i = 0; i < 4; ++i)
    dst[(long)(c0 + tr + i * 8) * dst_ld + r0 + tc] = (f16)tile[tc][tr + i * 8];
}

// ---------------------------------------------------------------------------
// GEMM: C[M][N] = A[M][K] fp16 x Bt[N][K] fp16, C fp16 or fp32.
// m97 structure: 128x128 tile, BK=64, linear LDS, global_load_lds 16B.
// ---------------------------------------------------------------------------
template <typename CT>
__global__ __launch_bounds__(256, 3) void gemm_f16(
    const f16* __restrict__ A, const f16* __restrict__ Bt,
    CT* __restrict__ C, int K, int N) {
  __shared__ f16 As[128][64];
  __shared__ f16 Bs[128][64];
  int tid = threadIdx.x, wave = tid >> 6, lane = tid & 63;
  int l16 = lane & 15, lhi = lane >> 4;
  int wm = (wave >> 1) * 64, wn = (wave & 1) * 64;
  long bm = (long)blockIdx.x * 128, bn = (long)blockIdx.y * 128;
  f32x4 acc[4][4] = {};

  int srow = wave * 32 + (lane >> 3);
  int scol = (lane & 7) * 8;
  const f16* Ag = A + (bm + srow) * (long)K + scol;
  const f16* Bg = Bt + (bn + srow) * (long)K + scol;

  for (int k0 = 0; k0 < K; k0 += 64) {
#pragma unroll
    for (int i = 0; i < 4; ++i)
      GLL16(Ag + k0 + (long)i * 8 * K, &As[wave * 32 + i * 8][0]);
#pragma unroll
    for (int i = 0; i < 4; ++i)
      GLL16(Bg + k0 + (long)i * 8 * K, &Bs[wave * 32 + i * 8][0]);
    __syncthreads();
#pragma unroll
    for (int kb = 0; kb < 2; ++kb) {
      f16x8 af[4], bf[4];
#pragma unroll
      for (int i = 0; i < 4; ++i)
        af[i] = *(const f16x8*)&As[wm + i * 16 + l16][kb * 32 + lhi * 8];
#pragma unroll
      for (int j = 0; j < 4; ++j)
        bf[j] = *(const f16x8*)&Bs[wn + j * 16 + l16][kb * 32 + lhi * 8];
#pragma unroll
      for (int i = 0; i < 4; ++i)
#pragma unroll
        for (int j = 0; j < 4; ++j)
          acc[i][j] =
              __builtin_amdgcn_mfma_f32_16x16x32_f16(bf[j], af[i], acc[i][j], 0, 0, 0);
    }
    __syncthreads();
  }

#pragma unroll
  for (int i = 0; i < 4; ++i) {
    long m = bm + wm + i * 16 + l16;
#pragma unroll
    for (int j = 0; j < 4; ++j) {
      long n = bn + wn + j * 16 + lhi * 4;
      if constexpr (sizeof(CT) == 2) {
        f16x4 h = {(f16)acc[i][j][0], (f16)acc[i][j][1], (f16)acc[i][j][2],
                   (f16)acc[i][j][3]};
        *(f16x4*)&C[m * N + n] = h;
      } else {
        *(f32x4*)&C[m * N + n] = acc[i][j];
      }
    }
  }
}

// ---------------------------------------------------------------------------
// RMSNorm + RoPE + scale, qkv fp16 -> Q/K fp16.  Vectorized: lane owns 4
// consecutive d (f16x4 loads); RoPE partner (d +/- 128) via shfl_xor(32).
// ---------------------------------------------------------------------------
__device__ __forceinline__ void norm_rope_store(
    const f16* __restrict__ x, const float* __restrict__ w,
    const float* __restrict__ fc, const float* __restrict__ fs,
    f16* __restrict__ dst, float scale, int lane) {
  int a = lane & 31, hi = lane >> 5;
  int d0 = 4 * a + 128 * hi;
  f16x4 xv = *(const f16x4*)(x + d0);
  float xf[4];
#pragma unroll
  for (int j = 0; j < 4; ++j) xf[j] = (float)xv[j];
  float ss = xf[0] * xf[0] + xf[1] * xf[1] + xf[2] * xf[2] + xf[3] * xf[3];
#pragma unroll
  for (int m = 1; m < 64; m <<= 1) ss += __shfl_xor(ss, m, 64);
  float inv = rsqrtf(ss * (1.0f / 256.0f) + 1e-6f);
  f32x4 wv = *(const f32x4*)(w + d0);
#pragma unroll
  for (int j = 0; j < 4; ++j) xf[j] *= inv * (1.0f + wv[j]);
  float pf[4];
#pragma unroll
  for (int j = 0; j < 4; ++j) pf[j] = __shfl_xor(xf[j], 32, 64);
  f32x4 c = *(const f32x4*)(fc + 4 * a);
  f32x4 s = *(const f32x4*)(fs + 4 * a);
  float sign = hi ? 1.0f : -1.0f;
  f16x4 out;
#pragma unroll
  for (int j = 0; j < 4; ++j)
    out[j] = (f16)((xf[j] * c[j] + sign * pf[j] * s[j]) * scale);
  *(f16x4*)(dst + d0) = out;
}

__global__ __launch_bounds__(256) void qkv_post(
    const f16* __restrict__ qkv, const float* __restrict__ qnw,
    const float* __restrict__ knw, const float* __restrict__ fcos,
    const float* __restrict__ fsin, f16* __restrict__ Q, f16* __restrict__ Kb) {
  long row = blockIdx.x;
  int b = (int)(row >> 11), s = (int)(row & 2047);
  int wave = threadIdx.x >> 6, lane = threadIdx.x & 63;
  const f16* base = qkv + row * QKV_N;
  const float* fc = fcos + (long)s * 128;
  const float* fs = fsin + (long)s * 128;
  norm_rope_store(base + wave * HD, qnw, fc, fs,
                  Q + ((long)(b * NH + wave) * SS + s) * HD, 0.0625f, lane);
  if (wave == 0)
    norm_rope_store(base + NH * HD, knw, fc, fs, Kb + row * HD, 1.0f, lane);
}

// ---------------------------------------------------------------------------
// Flash attention, causal, GQA. R9 structure (XCD-pinned grid, 63-item
// uniform kv-split, swizzled K/V LDS, swapped QK, in-reg softmax) +
// T14 async-split staging: tile t+1's global loads issued BEFORE compute of
// tile t (32 regs in flight, hidden under QK+softmax+PV) + T13 defer-max.
// launch_bounds(256,3): reg cap ~170 so the held regs don't spill.
// ---------------------------------------------------------------------------
__global__ __launch_bounds__(256, 3) void attn_fwd(
    const f16* __restrict__ Q, const f16* __restrict__ Kb,
    const f16* __restrict__ Vt, f16* __restrict__ O,
    f16* __restrict__ Opart, float2* __restrict__ ml) {
  __shared__ f16 Klds[32 * 256];
  __shared__ f16 Vlds[256 * 32];
  __shared__ f16 Plds[4][16][40];
  // --- XCD-pinned decode ---
  int bid = blockIdx.x;
  int xcd = bid & 7, slotid = bid >> 3;
  int b = xcd >> 1, par = xcd & 1;
  int h = slotid >> 5, ithalf = slotid & 31;
  int it = ithalf * 2 + par;
  if (it >= 63) return;

  int qb, t0, t1, slot = 0;
  bool split;
  if (it < 11) {
    qb = it; t0 = 0; t1 = 2 * qb + 2; split = false;
  } else {
    int j = it - 11, c, nch, lbase;
    if (j < 22) {
      qb = 11 + (j >> 1); c = j & 1; nch = 2; lbase = (qb - 11) * 2;
    } else {
      int jj = j - 22, q3 = jj / 3;
      qb = 22 + q3; c = jj - q3 * 3; nch = 3; lbase = 22 + q3 * 3;
    }
    int tiles = 2 * qb + 2;
    t0 = tiles * c / nch;
    t1 = tiles * (c + 1) / nch;
    split = true;
    slot = (b * NH + h) * 52 + lbase + c;
  }
  int tid = threadIdx.x, wave = tid >> 6, lane = tid & 63;
  int l16 = lane & 15, lhi = lane >> 4;
  int q0 = qb * 64 + wave * 16;

  const f16* Kg = Kb + (long)b * SS * HD;
  const f16* Vg = Vt + (long)b * HD * SS;

  // Q fragments (B-operand: q on lane&15, d-slice on lhi)
  f16x8 qf[8];
  const f16* Qbase = Q + ((long)(b * NH + h) * SS + q0 + l16) * HD + lhi * 8;
#pragma unroll
  for (int kb = 0; kb < 8; ++kb) qf[kb] = *(const f16x8*)(Qbase + kb * 32);

  f32x4 o[16] = {};
  float m_i = -1e30f, l_i = 0.f;

  // staging params (global reads linear/coalesced; LDS writes swizzled)
  int kr = tid >> 5, kc16 = (tid & 31) * 16;  // K rows kr+8i, col byte kc16
  int rv = tid >> 2, vc16 = (tid & 3) * 16;   // V rows rv+64i, col byte vc16
  char* kls = (char*)Klds;
  char* vls = (char*)Vlds;
  int kwsw = kc16 ^ (kr << 4);
  int vwsw = vc16 ^ ((rv & 3) << 4);
  const char* krd = kls + l16 * 512;
  int kswz = (l16 & 7) << 4;
  const char* vrd = vls + l16 * 64 + ((lhi * 16) ^ ((l16 & 3) << 4));

  // T14 prologue: tile t0 into regs
  uint4 kreg[4], vreg[4];
  {
    long kv0p = (long)t0 * 32;
#pragma unroll
    for (int i = 0; i < 4; ++i)
      kreg[i] = *(const uint4*)((const char*)(Kg + (kv0p + kr + 8 * i) * HD) + kc16);
#pragma unroll
    for (int i = 0; i < 4; ++i)
      vreg[i] = *(const uint4*)((const char*)(Vg + (long)(rv + 64 * i) * SS + kv0p) + vc16);
  }

  for (int t = t0; t < t1; ++t) {
    long kv0 = (long)t * 32;
    __syncthreads();  // prior tile's LDS reads complete
#pragma unroll
    for (int i = 0; i < 4; ++i)
      *(uint4*)(kls + (kr + 8 * i) * 512 + kwsw) = kreg[i];
#pragma unroll
    for (int i = 0; i < 4; ++i)
      *(uint4*)(vls + (rv + 64 * i) * 64 + vwsw) = vreg[i];
    if (t + 1 < t1) {  // issue next tile's loads; fly under compute
      long kn = (long)(t + 1) * 32;
#pragma unroll
      for (int i = 0; i < 4; ++i)
        kreg[i] = *(const uint4*)((const char*)(Kg + (kn + kr + 8 * i) * HD) + kc16);
#pragma unroll
      for (int i = 0; i < 4; ++i)
        vreg[i] = *(const uint4*)((const char*)(Vg + (long)(rv + 64 * i) * SS + kn) + vc16);
    }
    __syncthreads();  // staged tile visible

    // QK^T swapped: mfma(K, Q) -> D[kv_local][q=l16]
    f32x4 sc[2] = {};
    __builtin_amdgcn_s_setprio(1);
#pragma unroll
    for (int kb = 0; kb < 8; ++kb) {
#pragma unroll
      for (int cf = 0; cf < 2; ++cf) {
        f16x8 kf = *(const f16x8*)(krd + cf * 8192 + ((kb * 64 + lhi * 16) ^ kswz));
        sc[cf] = __builtin_amdgcn_mfma_f32_16x16x32_f16(kf, qf[kb], sc[cf], 0, 0, 0);
      }
    }
    __builtin_amdgcn_s_setprio(0);

    // online softmax: lane owns q-row q0+l16, 8 scores in-register
    float p[8];
    float mx = -1e30f;
    int qrow = q0 + l16;
    if (t >= 2 * qb) {  // diagonal tiles need the causal mask
#pragma unroll
      for (int cf = 0; cf < 2; ++cf)
#pragma unroll
        for (int r = 0; r < 4; ++r) {
          int kv = (int)kv0 + cf * 16 + lhi * 4 + r;
          float s = (kv <= qrow) ? sc[cf][r] : -1e30f;
          p[cf * 4 + r] = s;
          mx = fmaxf(mx, s);
        }
    } else {
#pragma unroll
      for (int i = 0; i < 8; ++i) {
        float s = sc[i >> 2][i & 3];
        p[i] = s;
        mx = fmaxf(mx, s);
      }
    }
    mx = fmaxf(mx, __shfl_xor(mx, 16));
    mx = fmaxf(mx, __shfl_xor(mx, 32));

    if (__all(mx <= m_i + 8.f)) {  // T13 defer-max: skip rescale
      float rs = 0.f;
#pragma unroll
      for (int i = 0; i < 8; ++i) {
        p[i] = __expf(p[i] - m_i);
        rs += p[i];
      }
      rs += __shfl_xor(rs, 16);
      rs += __shfl_xor(rs, 32);
      l_i += rs;
    } else {
      float mn = fmaxf(m_i, mx);
      float scl = __expf(m_i - mn);
      float rs = 0.f;
#pragma unroll
      for (int i = 0; i < 8; ++i) {
        p[i] = __expf(p[i] - mn);
        rs += p[i];
      }
      rs += __shfl_xor(rs, 16);
      rs += __shfl_xor(rs, 32);
      l_i = l_i * scl + rs;
      m_i = mn;
      float s0 = __shfl(scl, lhi * 4 + 0);
      float s1 = __shfl(scl, lhi * 4 + 1);
      float s2 = __shfl(scl, lhi * 4 + 2);
      float s3 = __shfl(scl, lhi * 4 + 3);
#pragma unroll
      for (int nf = 0; nf < 16; ++nf) {
        o[nf][0] *= s0;
        o[nf][1] *= s1;
        o[nf][2] *= s2;
        o[nf][3] *= s3;
      }
    }

    // P -> f16 into per-wave LDS [q][kv]
#pragma unroll
    for (int cf = 0; cf < 2; ++cf) {
      f16x4 hp = {(f16)p[cf * 4], (f16)p[cf * 4 + 1], (f16)p[cf * 4 + 2],
                  (f16)p[cf * 4 + 3]};
      *(f16x4*)&Plds[wave][l16][cf * 16 + lhi * 4] = hp;
    }

    // PV: o[q=lhi*4+r][d=nf*16+l16] += P x V
    f16x8 pa = *(const f16x8*)&Plds[wave][l16][lhi * 8];
    __builtin_amdgcn_s_setprio(1);
#pragma unroll
    for (int nf = 0; nf < 16; ++nf) {
      f16x8 vf = *(const f16x8*)(vrd + nf * 1024);
      o[nf] = __builtin_amdgcn_mfma_f32_16x16x32_f16(pa, vf, o[nf], 0, 0, 0);
    }
    __builtin_amdgcn_s_setprio(0);
  }

  // epilogue
  float inv = 1.0f / l_i;
  float i0 = __shfl(inv, lhi * 4 + 0);
  float i1 = __shfl(inv, lhi * 4 + 1);
  float i2 = __shfl(inv, lhi * 4 + 2);
  float i3 = __shfl(inv, lhi * 4 + 3);
  float ir[4] = {i0, i1, i2, i3};
  if (!split) {
#pragma unroll
    for (int r = 0; r < 4; ++r) {
      long srow = q0 + lhi * 4 + r;
      f16* Orow = O + ((long)b * SS + srow) * ODIM + h * HD + l16;
#pragma unroll
      for (int nf = 0; nf < 16; ++nf) Orow[nf * 16] = (f16)(o[nf][r] * ir[r]);
    }
  } else {
#pragma unroll
    for (int r = 0; r < 4; ++r) {
      int rloc = wave * 16 + lhi * 4 + r;
      f16* Prow = Opart + ((long)slot * 64 + rloc) * HD + l16;
#pragma unroll
      for (int nf = 0; nf < 16; ++nf) Prow[nf * 16] = (f16)(o[nf][r] * ir[r]);
    }
    if (lane < 16) {
      float2 v; v.x = m_i; v.y = l_i;
      ml[(long)slot * 64 + wave * 16 + lane] = v;
    }
  }
}

// ---------------------------------------------------------------------------
// Combine 2- or 3-way kv-split partials for qb in [11, 31].
// ---------------------------------------------------------------------------
__global__ __launch_bounds__(256) void attn_combine(
    const f16* __restrict__ Opart, const float2* __restrict__ ml,
    f16* __restrict__ O) {
  int x = blockIdx.x, h = blockIdx.y, b = blockIdx.z;
  int qb = 11 + x;
  int nch = (qb < 22) ? 2 : 3;
  int lbase = (qb < 22) ? (qb - 11) * 2 : 22 + (qb - 22) * 3;
  long slot0 = (long)(b * NH + h) * 52 + lbase;
  int tid = threadIdx.x;
  int r = tid >> 2, d0 = (tid & 3) * 64;
  float m[3], l[3], w[3];
  float M = -1e30f;
#pragma unroll
  for (int c = 0; c < 3; ++c)
    if (c < nch) {
      float2 v = ml[(slot0 + c) * 64 + r];
      m[c] = v.x; l[c] = v.y;
      M = fmaxf(M, v.x);
    }
  float sum = 0.f;
#pragma unroll
  for (int c = 0; c < 3; ++c)
    if (c < nch) { w[c] = l[c] * __expf(m[c] - M); sum += w[c]; }
  float inv = 1.0f / sum;
#pragma unroll
  for (int c = 0; c < 3; ++c)
    if (c < nch) w[c] *= inv;
  f16* Orow = O + ((long)b * SS + qb * 64 + r) * ODIM + h * HD + d0;
#pragma unroll
  for (int i = 0; i < 8; ++i) {
    float acc[8] = {};
#pragma unroll
    for (int c = 0; c < 3; ++c)
      if (c < nch) {
        f16x8 xv = *(const f16x8*)(Opart + ((slot0 + c) * 64 + r) * HD + d0 + i * 8);
#pragma unroll
        for (int j = 0; j < 8; ++j) acc[j] += w[c] * (float)xv[j];
      }
    f16x8 z;
#pragma unroll
    for (int j = 0; j < 8; ++j) z[j] = (f16)acc[j];
    *(f16x8*)(Orow + i * 8) = z;
  }
}

// ---------------------------------------------------------------------------
extern "C" void kernel_launch(void* const* d_in, const int* in_sizes, int n_in,
                              void* d_out, int out_size, void* d_ws, size_t ws_size,
                              hipStream_t stream) {
  const float* hidden = (const float*)d_in[0];
  const float* fcos = (const float*)d_in[2];
  const float* fsin = (const float*)d_in[3];
  const float* wqkv = (const float*)d_in[4];
  const float* qnw = (const float*)d_in[5];
  const float* knw = (const float*)d_in[6];
  const float* wo = (const float*)d_in[7];
  float* out = (float*)d_out;

  char* ws = (char*)d_ws;
  f16* qkv16 = (f16*)(ws + QKV16_OFF);
  f16* hid16 = (f16*)(ws + HID16_OFF);
  f16* Obuf = (f16*)(ws + OBUF_OFF);
  f16* Opart = (f16*)(ws + OPART_OFF);
  float2* ml = (float2*)(ws + ML_OFF);
  f16* Qb = (f16*)(ws + QB_OFF);
  f16* Kb = (f16*)(ws + KB_OFF);
  f16* Vt = (f16*)(ws + VT_OFF);
  f16* wqkvt = (f16*)(ws + WQKVT_OFF);
  f16* wot = (f16*)(ws + WOT_OFF);

  cvt_f32_to_f16<<<2048, 256, 0, stream>>>(hidden, hid16, (long)BB * SS * HID);

  transpose_weights<<<dim3(QKV_N / 32, HID / 32, 2), 256, 0, stream>>>(
      wqkv, wqkvt, wo, wot);

  gemm_f16<f16><<<dim3(BB * SS / 128, QKV_N / 128), 256, 0, stream>>>(
      hid16, wqkvt, qkv16, HID, QKV_N);

  qkv_post<<<dim3(BB * SS), 256, 0, stream>>>(qkv16, qnw, knw, fcos, fsin, Qb, Kb);

  transpose_cvt<f16><<<dim3(HD / 32, SS / 32, BB), 256, 0, stream>>>(
      qkv16 + 1280, QKV_N, (long)SS * QKV_N, Vt, SS, (long)HD * SS);

  attn_fwd<<<dim3(1024), 256, 0, stream>>>(Qb, Kb, Vt, Obuf, Opart, ml);
  attn_combine<<<dim3(21, NH, BB), 256, 0, stream>>>(Opart, ml, Obuf);

  gemm_f16<float><<<dim3(BB * SS / 128, HID / 128), 256, 0, stream>>>(
      Obuf, wot, out, ODIM, HID);
}

// Round 12
// 471.923 us; speedup vs baseline: 1.6157x; 1.1198x over previous
//
#include <hip/hip_runtime.h>

typedef _Float16 f16;
typedef _Float16 f16x8 __attribute__((ext_vector_type(8)));
typedef _Float16 f16x4 __attribute__((ext_vector_type(4)));
typedef float f32x4 __attribute__((ext_vector_type(4)));

#define NH 4
#define HD 256
#define BB 4
#define SS 2048
#define HID 1152
#define QKV_N 1536
#define ODIM (NH * HD)

#define QKV16_OFF 0L
#define HID16_OFF 25165824L
#define OBUF_OFF 0L
#define OPART_OFF 16777216L
#define ML_OFF 45088768L
#define QB_OFF 50331648L
#define KB_OFF 67108864L
#define VT_OFF 71303168L
#define WQKVT_OFF 75497472L
#define WOT_OFF 79036416L

// async global->LDS, 16B per lane; LDS dest = wave-uniform base + lane*16
#define GLL16(gp, lp)                                                      \
  __builtin_amdgcn_global_load_lds(                                       \
      (const __attribute__((address_space(1))) char*)(gp),                \
      (__attribute__((address_space(3))) char*)(lp), 16, 0, 0)

// ---------------------------------------------------------------------------
// fp32 -> fp16 bulk convert (vectorized, grid-stride)
// ---------------------------------------------------------------------------
__global__ __launch_bounds__(256) void cvt_f32_to_f16(
    const float* __restrict__ s, f16* __restrict__ d, long n) {
  long i = ((long)blockIdx.x * 256 + threadIdx.x) * 8;
  long stride = (long)gridDim.x * 256 * 8;
  for (; i < n; i += stride) {
    float4 a = *(const float4*)(s + i);
    float4 b = *(const float4*)(s + i + 4);
    f16x8 h = {(f16)a.x, (f16)a.y, (f16)a.z, (f16)a.w,
               (f16)b.x, (f16)b.y, (f16)b.z, (f16)b.w};
    *(f16x8*)(d + i) = h;
  }
}

// ---------------------------------------------------------------------------
// Both weight transposes in one dispatch (z selects which).
// ---------------------------------------------------------------------------
__global__ __launch_bounds__(256) void transpose_weights(
    const float* __restrict__ w1, f16* __restrict__ d1,
    const float* __restrict__ w2, f16* __restrict__ d2) {
  __shared__ float tile[32][33];
  const float* src;
  f16* dst;
  long sld, dld;
  if (blockIdx.z == 0) {
    src = w1; dst = d1; sld = QKV_N; dld = HID;
  } else {
    if (blockIdx.x >= HID / 32 || blockIdx.y >= ODIM / 32) return;
    src = w2; dst = d2; sld = HID; dld = ODIM;
  }
  int r0 = blockIdx.y * 32, c0 = blockIdx.x * 32;
  int tc = threadIdx.x & 31, tr = threadIdx.x >> 5;
#pragma unroll
  for (int i = 0; i < 4; ++i)
    tile[tr + i * 8][tc] = src[(long)(r0 + tr + i * 8) * sld + c0 + tc];
  __syncthreads();
#pragma unroll
  for (int i = 0; i < 4; ++i)
    dst[(long)(c0 + tr + i * 8) * dld + r0 + tc] = (f16)tile[tc][tr + i * 8];
}

// ---------------------------------------------------------------------------
// Transpose + convert to fp16:  dst[c][r] = (f16) src[r][c]   (V slice)
// ---------------------------------------------------------------------------
template <typename ST>
__global__ __launch_bounds__(256) void transpose_cvt(
    const ST* __restrict__ src, long src_ld, long src_bs,
    f16* __restrict__ dst, long dst_ld, long dst_bs) {
  __shared__ float tile[32][33];
  src += (long)blockIdx.z * src_bs;
  dst += (long)blockIdx.z * dst_bs;
  int r0 = blockIdx.y * 32, c0 = blockIdx.x * 32;
  int tc = threadIdx.x & 31, tr = threadIdx.x >> 5;
#pragma unroll
  for (int i = 0; i < 4; ++i)
    tile[tr + i * 8][tc] = (float)src[(long)(r0 + tr + i * 8) * src_ld + c0 + tc];
  __syncthreads();
#pragma unroll
  for (int i = 0; i < 4; ++i)
    dst[(long)(c0 + tr + i * 8) * dst_ld + r0 + tc] = (f16)tile[tc][tr + i * 8];
}

// ---------------------------------------------------------------------------
// GEMM: C[M][N] = A[M][K] fp16 x Bt[N][K] fp16, C fp16 or fp32.
// m97 structure: 128x128 tile, BK=64, linear LDS, global_load_lds 16B.
// ---------------------------------------------------------------------------
template <typename CT>
__global__ __launch_bounds__(256, 3) void gemm_f16(
    const f16* __restrict__ A, const f16* __restrict__ Bt,
    CT* __restrict__ C, int K, int N) {
  __shared__ f16 As[128][64];
  __shared__ f16 Bs[128][64];
  int tid = threadIdx.x, wave = tid >> 6, lane = tid & 63;
  int l16 = lane & 15, lhi = lane >> 4;
  int wm = (wave >> 1) * 64, wn = (wave & 1) * 64;
  long bm = (long)blockIdx.x * 128, bn = (long)blockIdx.y * 128;
  f32x4 acc[4][4] = {};

  int srow = wave * 32 + (lane >> 3);
  int scol = (lane & 7) * 8;
  const f16* Ag = A + (bm + srow) * (long)K + scol;
  const f16* Bg = Bt + (bn + srow) * (long)K + scol;

  for (int k0 = 0; k0 < K; k0 += 64) {
#pragma unroll
    for (int i = 0; i < 4; ++i)
      GLL16(Ag + k0 + (long)i * 8 * K, &As[wave * 32 + i * 8][0]);
#pragma unroll
    for (int i = 0; i < 4; ++i)
      GLL16(Bg + k0 + (long)i * 8 * K, &Bs[wave * 32 + i * 8][0]);
    __syncthreads();
#pragma unroll
    for (int kb = 0; kb < 2; ++kb) {
      f16x8 af[4], bf[4];
#pragma unroll
      for (int i = 0; i < 4; ++i)
        af[i] = *(const f16x8*)&As[wm + i * 16 + l16][kb * 32 + lhi * 8];
#pragma unroll
      for (int j = 0; j < 4; ++j)
        bf[j] = *(const f16x8*)&Bs[wn + j * 16 + l16][kb * 32 + lhi * 8];
#pragma unroll
      for (int i = 0; i < 4; ++i)
#pragma unroll
        for (int j = 0; j < 4; ++j)
          acc[i][j] =
              __builtin_amdgcn_mfma_f32_16x16x32_f16(bf[j], af[i], acc[i][j], 0, 0, 0);
    }
    __syncthreads();
  }

#pragma unroll
  for (int i = 0; i < 4; ++i) {
    long m = bm + wm + i * 16 + l16;
#pragma unroll
    for (int j = 0; j < 4; ++j) {
      long n = bn + wn + j * 16 + lhi * 4;
      if constexpr (sizeof(CT) == 2) {
        f16x4 h = {(f16)acc[i][j][0], (f16)acc[i][j][1], (f16)acc[i][j][2],
                   (f16)acc[i][j][3]};
        *(f16x4*)&C[m * N + n] = h;
      } else {
        *(f32x4*)&C[m * N + n] = acc[i][j];
      }
    }
  }
}

// ---------------------------------------------------------------------------
// RMSNorm + RoPE + scale, qkv fp16 -> Q/K fp16 (vectorized, R11-proven).
// ---------------------------------------------------------------------------
__device__ __forceinline__ void norm_rope_store(
    const f16* __restrict__ x, const float* __restrict__ w,
    const float* __restrict__ fc, const float* __restrict__ fs,
    f16* __restrict__ dst, float scale, int lane) {
  int a = lane & 31, hi = lane >> 5;
  int d0 = 4 * a + 128 * hi;
  f16x4 xv = *(const f16x4*)(x + d0);
  float xf[4];
#pragma unroll
  for (int j = 0; j < 4; ++j) xf[j] = (float)xv[j];
  float ss = xf[0] * xf[0] + xf[1] * xf[1] + xf[2] * xf[2] + xf[3] * xf[3];
#pragma unroll
  for (int m = 1; m < 64; m <<= 1) ss += __shfl_xor(ss, m, 64);
  float inv = rsqrtf(ss * (1.0f / 256.0f) + 1e-6f);
  f32x4 wv = *(const f32x4*)(w + d0);
#pragma unroll
  for (int j = 0; j < 4; ++j) xf[j] *= inv * (1.0f + wv[j]);
  float pf[4];
#pragma unroll
  for (int j = 0; j < 4; ++j) pf[j] = __shfl_xor(xf[j], 32, 64);
  f32x4 c = *(const f32x4*)(fc + 4 * a);
  f32x4 s = *(const f32x4*)(fs + 4 * a);
  float sign = hi ? 1.0f : -1.0f;
  f16x4 out;
#pragma unroll
  for (int j = 0; j < 4; ++j)
    out[j] = (f16)((xf[j] * c[j] + sign * pf[j] * s[j]) * scale);
  *(f16x4*)(dst + d0) = out;
}

__global__ __launch_bounds__(256) void qkv_post(
    const f16* __restrict__ qkv, const float* __restrict__ qnw,
    const float* __restrict__ knw, const float* __restrict__ fcos,
    const float* __restrict__ fsin, f16* __restrict__ Q, f16* __restrict__ Kb) {
  long row = blockIdx.x;
  int b = (int)(row >> 11), s = (int)(row & 2047);
  int wave = threadIdx.x >> 6, lane = threadIdx.x & 63;
  const f16* base = qkv + row * QKV_N;
  const float* fc = fcos + (long)s * 128;
  const float* fs = fsin + (long)s * 128;
  norm_rope_store(base + wave * HD, qnw, fc, fs,
                  Q + ((long)(b * NH + wave) * SS + s) * HD, 0.0625f, lane);
  if (wave == 0)
    norm_rope_store(base + NH * HD, knw, fc, fs, Kb + row * HD, 1.0f, lane);
}

// ---------------------------------------------------------------------------
// Flash attention, causal, GQA. R9 per-wave body, but 8 waves (512 thr) per
// block sharing each staged K/V tile (128 q-rows/block): staging cost per
// unit work halved. 32 uniform items per (b,h): macros m=0..4 whole,
// m=5..10 2-way kv-split, m=11..15 3-way (chunks <= 22 tiles).
// grid 512 blocks = 2/CU, XCD-pinned (one batch per XCD).
// ---------------------------------------------------------------------------
__global__ __launch_bounds__(512, 4) void attn_fwd(
    const f16* __restrict__ Q, const f16* __restrict__ Kb,
    const f16* __restrict__ Vt, f16* __restrict__ O,
    f16* __restrict__ Opart, float2* __restrict__ ml) {
  __shared__ f16 Klds[32 * 256];   // [kv][d], XOR-swizzled ^((row&7)<<4)
  __shared__ f16 Vlds[256 * 32];   // [d][kv], XOR-swizzled ^((row&3)<<4)
  __shared__ f16 Plds[8][16][40];  // per-wave P tile [q][kv]
  // --- XCD-pinned decode ---
  int bid = blockIdx.x;
  int xcd = bid & 7, slotid = bid >> 3;
  int b = xcd >> 1, par = xcd & 1;
  int h = slotid >> 4, itp = slotid & 15;
  int it = itp * 2 + par;  // 0..31

  int m, c, nch;
  if (it < 5) {
    m = it; c = 0; nch = 1;
  } else if (it < 17) {
    int j = it - 5; m = 5 + (j >> 1); c = j & 1; nch = 2;
  } else {
    int j = it - 17; int q3 = j / 3; m = 11 + q3; c = j - q3 * 3; nch = 3;
  }
  int tiles = 4 * m + 4;
  int t0 = tiles * c / nch, t1 = tiles * (c + 1) / nch;
  bool split = nch > 1;
  int slot = 0;
  if (split) {
    int sbase = (m <= 10) ? (m - 5) * 2 : 12 + (m - 11) * 3;
    slot = (b * NH + h) * 27 + sbase + c;
  }
  int tid = threadIdx.x, wave = tid >> 6, lane = tid & 63;
  int l16 = lane & 15, lhi = lane >> 4;
  int q0 = m * 128 + wave * 16;

  const f16* Kg = Kb + (long)b * SS * HD;
  const f16* Vg = Vt + (long)b * HD * SS;

  // Q fragments (B-operand: q on lane&15, d-slice on lhi)
  f16x8 qf[8];
  const f16* Qbase = Q + ((long)(b * NH + h) * SS + q0 + l16) * HD + lhi * 8;
#pragma unroll
  for (int kb = 0; kb < 8; ++kb) qf[kb] = *(const f16x8*)(Qbase + kb * 32);

  f32x4 o[16] = {};
  float m_i = -1e30f, l_i = 0.f;

  // staging (512 threads): K row tid>>4, half-row (tid&15)*16 + i*256
  //                        V rows (tid>>2)+128i, col (tid&3)*16
  int krow = tid >> 4, kcb = (tid & 15) * 16;
  int vrow = tid >> 2, vcb = (tid & 3) * 16;
  char* kls = (char*)Klds;
  char* vls = (char*)Vlds;
  int kwsw = kcb ^ ((krow & 7) << 4);
  int vwsw = vcb ^ ((vrow & 3) << 4);
  const char* krd = kls + l16 * 512;
  int kswz = (l16 & 7) << 4;
  const char* vrd = vls + l16 * 64 + ((lhi * 16) ^ ((l16 & 3) << 4));

  for (int t = t0; t < t1; ++t) {
    long kv0 = (long)t * 32;
    __syncthreads();  // prior tile's LDS reads complete
#pragma unroll
    for (int i = 0; i < 2; ++i) {
      uint4 kval = *(const uint4*)((const char*)(Kg + (kv0 + krow) * HD) + kcb + i * 256);
      *(uint4*)(kls + krow * 512 + kwsw + i * 256) = kval;
    }
#pragma unroll
    for (int i = 0; i < 2; ++i) {
      uint4 vval = *(const uint4*)((const char*)(Vg + (long)(vrow + 128 * i) * SS + kv0) + vcb);
      *(uint4*)(vls + (vrow + 128 * i) * 64 + vwsw) = vval;
    }
    __syncthreads();  // staged tile visible

    // QK^T swapped: mfma(K, Q) -> D[kv_local][q=l16]
    f32x4 sc[2] = {};
    __builtin_amdgcn_s_setprio(1);
#pragma unroll
    for (int kb = 0; kb < 8; ++kb) {
#pragma unroll
      for (int cf = 0; cf < 2; ++cf) {
        f16x8 kf = *(const f16x8*)(krd + cf * 8192 + ((kb * 64 + lhi * 16) ^ kswz));
        sc[cf] = __builtin_amdgcn_mfma_f32_16x16x32_f16(kf, qf[kb], sc[cf], 0, 0, 0);
      }
    }
    __builtin_amdgcn_s_setprio(0);

    // online softmax: lane owns q-row q0+l16, 8 scores in-register
    float p[8];
    float mx = -1e30f;
    int qrow = q0 + l16;
    if ((int)kv0 + 31 > q0) {  // tile touches/passes this wave's diagonal
#pragma unroll
      for (int cf = 0; cf < 2; ++cf)
#pragma unroll
        for (int r = 0; r < 4; ++r) {
          int kv = (int)kv0 + cf * 16 + lhi * 4 + r;
          float s = (kv <= qrow) ? sc[cf][r] : -1e30f;
          p[cf * 4 + r] = s;
          mx = fmaxf(mx, s);
        }
    } else {
#pragma unroll
      for (int i = 0; i < 8; ++i) {
        float s = sc[i >> 2][i & 3];
        p[i] = s;
        mx = fmaxf(mx, s);
      }
    }
    mx = fmaxf(mx, __shfl_xor(mx, 16));
    mx = fmaxf(mx, __shfl_xor(mx, 32));

    if (__all(mx <= m_i + 8.f)) {  // T13 defer-max: skip rescale
      float rs = 0.f;
#pragma unroll
      for (int i = 0; i < 8; ++i) {
        p[i] = __expf(p[i] - m_i);
        rs += p[i];
      }
      rs += __shfl_xor(rs, 16);
      rs += __shfl_xor(rs, 32);
      l_i += rs;
    } else {
      float mn = fmaxf(m_i, mx);
      float scl = __expf(m_i - mn);
      float rs = 0.f;
#pragma unroll
      for (int i = 0; i < 8; ++i) {
        p[i] = __expf(p[i] - mn);
        rs += p[i];
      }
      rs += __shfl_xor(rs, 16);
      rs += __shfl_xor(rs, 32);
      l_i = l_i * scl + rs;
      m_i = mn;
      float s0 = __shfl(scl, lhi * 4 + 0);
      float s1 = __shfl(scl, lhi * 4 + 1);
      float s2 = __shfl(scl, lhi * 4 + 2);
      float s3 = __shfl(scl, lhi * 4 + 3);
#pragma unroll
      for (int nf = 0; nf < 16; ++nf) {
        o[nf][0] *= s0;
        o[nf][1] *= s1;
        o[nf][2] *= s2;
        o[nf][3] *= s3;
      }
    }

    // P -> f16 into per-wave LDS [q][kv]
#pragma unroll
    for (int cf = 0; cf < 2; ++cf) {
      f16x4 hp = {(f16)p[cf * 4], (f16)p[cf * 4 + 1], (f16)p[cf * 4 + 2],
                  (f16)p[cf * 4 + 3]};
      *(f16x4*)&Plds[wave][l16][cf * 16 + lhi * 4] = hp;
    }

    // PV: o[q=lhi*4+r][d=nf*16+l16] += P x V
    f16x8 pa = *(const f16x8*)&Plds[wave][l16][lhi * 8];
    __builtin_amdgcn_s_setprio(1);
#pragma unroll
    for (int nf = 0; nf < 16; ++nf) {
      f16x8 vf = *(const f16x8*)(vrd + nf * 1024);
      o[nf] = __builtin_amdgcn_mfma_f32_16x16x32_f16(pa, vf, o[nf], 0, 0, 0);
    }
    __builtin_amdgcn_s_setprio(0);
  }

  // epilogue
  float inv = 1.0f / l_i;
  float i0 = __shfl(inv, lhi * 4 + 0);
  float i1 = __shfl(inv, lhi * 4 + 1);
  float i2 = __shfl(inv, lhi * 4 + 2);
  float i3 = __shfl(inv, lhi * 4 + 3);
  float ir[4] = {i0, i1, i2, i3};
  if (!split) {
#pragma unroll
    for (int r = 0; r < 4; ++r) {
      long srow = q0 + lhi * 4 + r;
      f16* Orow = O + ((long)b * SS + srow) * ODIM + h * HD + l16;
#pragma unroll
      for (int nf = 0; nf < 16; ++nf) Orow[nf * 16] = (f16)(o[nf][r] * ir[r]);
    }
  } else {
#pragma unroll
    for (int r = 0; r < 4; ++r) {
      int rloc = wave * 16 + lhi * 4 + r;
      f16* Prow = Opart + ((long)slot * 128 + rloc) * HD + l16;
#pragma unroll
      for (int nf = 0; nf < 16; ++nf) Prow[nf * 16] = (f16)(o[nf][r] * ir[r]);
    }
    if (lane < 16) {
      float2 v; v.x = m_i; v.y = l_i;
      ml[(long)slot * 128 + wave * 16 + lane] = v;
    }
  }
}

// ---------------------------------------------------------------------------
// Combine 2- or 3-way kv-split partials for macros m in [5, 15].
// grid (11, NH, B), 256 thr: thread = (row 0..127, half-of-d)
// ---------------------------------------------------------------------------
__global__ __launch_bounds__(256) void attn_combine(
    const f16* __restrict__ Opart, const float2* __restrict__ ml,
    f16* __restrict__ O) {
  int x = blockIdx.x, h = blockIdx.y, b = blockIdx.z;
  int m = 5 + x;
  int nch = (m <= 10) ? 2 : 3;
  int sbase = (m <= 10) ? (m - 5) * 2 : 12 + (m - 11) * 3;
  long slot0 = (long)(b * NH + h) * 27 + sbase;
  int tid = threadIdx.x;
  int r = tid >> 1, d0 = (tid & 1) * 128;
  float mm[3], ll[3], w[3];
  float M = -1e30f;
#pragma unroll
  for (int c = 0; c < 3; ++c)
    if (c < nch) {
      float2 v = ml[(slot0 + c) * 128 + r];
      mm[c] = v.x; ll[c] = v.y;
      M = fmaxf(M, v.x);
    }
  float sum = 0.f;
#pragma unroll
  for (int c = 0; c < 3; ++c)
    if (c < nch) { w[c] = ll[c] * __expf(mm[c] - M); sum += w[c]; }
  float inv = 1.0f / sum;
#pragma unroll
  for (int c = 0; c < 3; ++c)
    if (c < nch) w[c] *= inv;
  f16* Orow = O + ((long)b * SS + m * 128 + r) * ODIM + h * HD + d0;
#pragma unroll
  for (int i = 0; i < 16; ++i) {
    float acc[8] = {};
#pragma unroll
    for (int c = 0; c < 3; ++c)
      if (c < nch) {
        f16x8 xv = *(const f16x8*)(Opart + ((slot0 + c) * 128 + r) * HD + d0 + i * 8);
#pragma unroll
        for (int j = 0; j < 8; ++j) acc[j] += w[c] * (float)xv[j];
      }
    f16x8 z;
#pragma unroll
    for (int j = 0; j < 8; ++j) z[j] = (f16)acc[j];
    *(f16x8*)(Orow + i * 8) = z;
  }
}

// ---------------------------------------------------------------------------
extern "C" void kernel_launch(void* const* d_in, const int* in_sizes, int n_in,
                              void* d_out, int out_size, void* d_ws, size_t ws_size,
                              hipStream_t stream) {
  const float* hidden = (const float*)d_in[0];
  const float* fcos = (const float*)d_in[2];
  const float* fsin = (const float*)d_in[3];
  const float* wqkv = (const float*)d_in[4];
  const float* qnw = (const float*)d_in[5];
  const float* knw = (const float*)d_in[6];
  const float* wo = (const float*)d_in[7];
  float* out = (float*)d_out;

  char* ws = (char*)d_ws;
  f16* qkv16 = (f16*)(ws + QKV16_OFF);   // dead after V-transpose
  f16* hid16 = (f16*)(ws + HID16_OFF);   // dead after gemm1
  f16* Obuf = (f16*)(ws + OBUF_OFF);
  f16* Opart = (f16*)(ws + OPART_OFF);   // 432 slots x 128 x 256 f16 = 28.3MB
  float2* ml = (float2*)(ws + ML_OFF);   // 432 x 128 x 8B = 0.44MB
  f16* Qb = (f16*)(ws + QB_OFF);
  f16* Kb = (f16*)(ws + KB_OFF);
  f16* Vt = (f16*)(ws + VT_OFF);
  f16* wqkvt = (f16*)(ws + WQKVT_OFF);
  f16* wot = (f16*)(ws + WOT_OFF);

  cvt_f32_to_f16<<<2048, 256, 0, stream>>>(hidden, hid16, (long)BB * SS * HID);

  transpose_weights<<<dim3(QKV_N / 32, HID / 32, 2), 256, 0, stream>>>(
      wqkv, wqkvt, wo, wot);

  gemm_f16<f16><<<dim3(BB * SS / 128, QKV_N / 128), 256, 0, stream>>>(
      hid16, wqkvt, qkv16, HID, QKV_N);

  qkv_post<<<dim3(BB * SS), 256, 0, stream>>>(qkv16, qnw, knw, fcos, fsin, Qb, Kb);

  transpose_cvt<f16><<<dim3(HD / 32, SS / 32, BB), 256, 0, stream>>>(
      qkv16 + 1280, QKV_N, (long)SS * QKV_N, Vt, SS, (long)HD * SS);

  attn_fwd<<<dim3(512), 512, 0, stream>>>(Qb, Kb, Vt, Obuf, Opart, ml);
  attn_combine<<<dim3(11, NH, BB), 256, 0, stream>>>(Opart, ml, Obuf);

  gemm_f16<float><<<dim3(BB * SS / 128, HID / 128), 256, 0, stream>>>(
      Obuf, wot, out, ODIM, HID);
}